// Round 13
// baseline (92.601 us; speedup 1.0000x reference)
//
#include <hip/hip_runtime.h>
#include <hip/hip_bf16.h>
#include <stdint.h>

// RNDiscriminator: B=64, d^2=64 positions, 26 features, g: 52->256->256, f: 256->1
// h1[i,j] = relu(u'[j] + v[i]); dominant cost sum_ij relu(h1 @ W2 + b2) = 34.4 GF bf16.
//
// R13: FULL FRONT-END FUSION. k_main block = (b, i-quarter): in-block conv+coords
// -> xs (LDS), in-block u'/v (LDS, 4x redundant across i-quarters -- 1.3% extra
// FLOPs, saves k12+k2b launches and all u/v global traffic), consumers build
// Bf[8][4] from global w2 (same cvt_pk rounding). Pair loop = R12's
// producer/consumer flag-synced ring, unchanged. LDS overlay: xs & us live in
// ring slots 0-2, dead (barrier) before the ring is first written.

typedef float f32x4 __attribute__((ext_vector_type(4)));
typedef float f32x2 __attribute__((ext_vector_type(2)));
typedef short short8 __attribute__((ext_vector_type(8)));
typedef int   int4v  __attribute__((ext_vector_type(4)));

#define NB 4   // ring depth

__device__ __forceinline__ uint32_t cvt_pk_bf16(float lo, float hi) {
    uint32_t r;
    asm("v_cvt_pk_bf16_f32 %0, %1, %2" : "=v"(r) : "v"(lo), "v"(hi));
    return r;
}
__device__ __forceinline__ f32x2 relu2(f32x2 a) {
    f32x2 z = (f32x2){0.f, 0.f};
    return __builtin_elementwise_max(a, z);
}
__device__ __forceinline__ void spin_eq(int* p, int val) {
    while (__hip_atomic_load(p, __ATOMIC_ACQUIRE, __HIP_MEMORY_SCOPE_WORKGROUP) != val)
        __builtin_amdgcn_s_sleep(1);
    __builtin_amdgcn_sched_barrier(0);
}
__device__ __forceinline__ void flag_release_add(int* p, int lane) {
    asm volatile("s_waitcnt lgkmcnt(0)" ::: "memory");
    if (lane == 0)
        __hip_atomic_fetch_add(p, 1, __ATOMIC_RELEASE, __HIP_MEMORY_SCOPE_WORKGROUP);
}

// ---- consumer macros (identical to R12) ----
#define C_READ(A, KS)                                                  \
    { const char* hx = ((KS) & 1) ? hO : hE;                           \
      A[0] = *(const short8*)(hx + ((KS) >> 1) * 128);                 \
      A[1] = *(const short8*)(hx + 8192  + ((KS) >> 1) * 128);         \
      A[2] = *(const short8*)(hx + 16384 + ((KS) >> 1) * 128);         \
      A[3] = *(const short8*)(hx + 24576 + ((KS) >> 1) * 128); }

#define C_MFMA(A, KS)                                                  \
    { acc[0][0] = __builtin_amdgcn_mfma_f32_16x16x32_bf16(A[0], Bf[KS][0], acc[0][0], 0,0,0); \
      acc[1][0] = __builtin_amdgcn_mfma_f32_16x16x32_bf16(A[1], Bf[KS][0], acc[1][0], 0,0,0); \
      acc[2][0] = __builtin_amdgcn_mfma_f32_16x16x32_bf16(A[2], Bf[KS][0], acc[2][0], 0,0,0); \
      acc[3][0] = __builtin_amdgcn_mfma_f32_16x16x32_bf16(A[3], Bf[KS][0], acc[3][0], 0,0,0); \
      acc[0][1] = __builtin_amdgcn_mfma_f32_16x16x32_bf16(A[0], Bf[KS][1], acc[0][1], 0,0,0); \
      acc[1][1] = __builtin_amdgcn_mfma_f32_16x16x32_bf16(A[1], Bf[KS][1], acc[1][1], 0,0,0); \
      acc[2][1] = __builtin_amdgcn_mfma_f32_16x16x32_bf16(A[2], Bf[KS][1], acc[2][1], 0,0,0); \
      acc[3][1] = __builtin_amdgcn_mfma_f32_16x16x32_bf16(A[3], Bf[KS][1], acc[3][1], 0,0,0); \
      acc[0][2] = __builtin_amdgcn_mfma_f32_16x16x32_bf16(A[0], Bf[KS][2], acc[0][2], 0,0,0); \
      acc[1][2] = __builtin_amdgcn_mfma_f32_16x16x32_bf16(A[1], Bf[KS][2], acc[1][2], 0,0,0); \
      acc[2][2] = __builtin_amdgcn_mfma_f32_16x16x32_bf16(A[2], Bf[KS][2], acc[2][2], 0,0,0); \
      acc[3][2] = __builtin_amdgcn_mfma_f32_16x16x32_bf16(A[3], Bf[KS][2], acc[3][2], 0,0,0); \
      acc[0][3] = __builtin_amdgcn_mfma_f32_16x16x32_bf16(A[0], Bf[KS][3], acc[0][3], 0,0,0); \
      acc[1][3] = __builtin_amdgcn_mfma_f32_16x16x32_bf16(A[1], Bf[KS][3], acc[1][3], 0,0,0); \
      acc[2][3] = __builtin_amdgcn_mfma_f32_16x16x32_bf16(A[2], Bf[KS][3], acc[2][3], 0,0,0); \
      acc[3][3] = __builtin_amdgcn_mfma_f32_16x16x32_bf16(A[3], Bf[KS][3], acc[3][3], 0,0,0); }

__global__ __launch_bounds__(512, 2) void k_main(
        const float* __restrict__ img, const float* __restrict__ cw,
        const float* __restrict__ cb, const float* __restrict__ w1,
        const float* __restrict__ b1, const float* __restrict__ w2,
        const float* __restrict__ b2, float* __restrict__ part) {
    __shared__ short h1s[NB][64 * 256];   // 128 KB ring (slots 0-2 overlaid below)
    __shared__ float vsm[16][256];        // 16 KB
    __shared__ int prod_cnt[16];
    __shared__ int cons_cnt[16];
    int t = threadIdx.x;
    int lane = t & 63, wv = t >> 6;
    int blk = blockIdx.x;                 // 0..255
    int b = blk & 63, i0 = (blk >> 6) * 16;

    if (t < 16) { prod_cnt[t] = 0; cons_cnt[t] = 0; }

    float* xs = (float*)&h1s[0][0];                 // [64][26], 6.5 KB (slot 0)
    float* us = (float*)((char*)&h1s[0][0] + 32768); // [64][256] f32, 64 KB (slots 1-2)

    // ---- phase A: conv 8x8/s8 + relu + coords -> xs[pos][ch] ----
    for (int idx = t; idx < 1664; idx += 512) {
        int pos = idx / 26;
        int ch  = idx - pos * 26;
        int r = pos >> 3, c = pos & 7;
        float val;
        if (ch < 24) {
            float s = cb[ch];
            #pragma unroll
            for (int ci = 0; ci < 3; ++ci)
                #pragma unroll
                for (int kr = 0; kr < 8; ++kr) {
                    const float* ip = img + ((b * 3 + ci) * 64 + r * 8 + kr) * 64 + c * 8;
                    const float* wp = cw + ((ch * 3 + ci) * 8 + kr) * 8;
                    float4 a0 = *(const float4*)ip;
                    float4 a1 = *(const float4*)(ip + 4);
                    float4 q0 = *(const float4*)wp;
                    float4 q1 = *(const float4*)(wp + 4);
                    s += a0.x * q0.x + a0.y * q0.y + a0.z * q0.z + a0.w * q0.w
                       + a1.x * q1.x + a1.y * q1.y + a1.z * q1.z + a1.w * q1.w;
                }
            val = fmaxf(s, 0.f);
        } else if (ch == 24) {
            val = -1.f + (2.f / 7.f) * (float)c;
        } else {
            val = -1.f + (2.f / 7.f) * (float)r;
        }
        xs[pos * 26 + ch] = val;
    }
    __syncthreads();

    // ---- phase B: u'[j][c] (all 64 rows) and v[i0+q][c] (16 rows) ----
    {
        int c = t & 255, half = t >> 8;   // half 0/1
        float su[32], sv[8];
        float bc = b1[c];
        #pragma unroll
        for (int r = 0; r < 32; ++r) su[r] = bc;
        #pragma unroll
        for (int r = 0; r < 8; ++r) sv[r] = 0.f;
        int ur0 = half * 32;
        int vr0 = i0 + half * 8;
        #pragma unroll 2
        for (int k = 0; k < 26; ++k) {
            float wu  = w1[k * 256 + c];
            float wvv = w1[(26 + k) * 256 + c];
            #pragma unroll
            for (int r = 0; r < 32; ++r) su[r] += xs[(ur0 + r) * 26 + k] * wu;
            #pragma unroll
            for (int r = 0; r < 8; ++r)  sv[r] += xs[(vr0 + r) * 26 + k] * wvv;
        }
        #pragma unroll
        for (int r = 0; r < 32; ++r) us[(ur0 + r) * 256 + c] = su[r];
        #pragma unroll
        for (int r = 0; r < 8; ++r)  vsm[half * 8 + r][c] = sv[r];
    }
    __syncthreads();   // xs dead; us/vsm ready

    if (wv < 4) {
        // ================= PRODUCER (waves 0-3, one per SIMD) =================
        int col8 = t & 31, rq = t >> 5;   // t in 0..255: rows rq*8..+8, cols col8*8..+8
        f32x4 u0[8], u1[8];
        #pragma unroll
        for (int rr = 0; rr < 8; ++rr) {
            u0[rr] = *(const f32x4*)(us + (rq * 8 + rr) * 256 + col8 * 8);
            u1[rr] = *(const f32x4*)(us + (rq * 8 + rr) * 256 + col8 * 8 + 4);
        }
        int wbase = rq * 8 * 512;
        int c16 = col8 * 16;
        __syncthreads();   // ALL u-reg loads done before ring overwrites us

        #pragma unroll 1
        for (int q = 0; q < 16; ++q) {
            if (q >= NB) spin_eq(&cons_cnt[q - NB], 4);
            char* wbuf = (char*)h1s[q & (NB - 1)] + wbase;
            f32x4 va = *(const f32x4*)&vsm[q][col8 * 8];
            f32x4 vb = *(const f32x4*)&vsm[q][col8 * 8 + 4];
            #pragma unroll
            for (int rr = 0; rr < 8; ++rr) {   // row = rq*8+rr, row&7 == rr
                f32x2 a0 = relu2((f32x2){u0[rr].x, u0[rr].y} + (f32x2){va.x, va.y});
                f32x2 a1 = relu2((f32x2){u0[rr].z, u0[rr].w} + (f32x2){va.z, va.w});
                f32x2 a2 = relu2((f32x2){u1[rr].x, u1[rr].y} + (f32x2){vb.x, vb.y});
                f32x2 a3 = relu2((f32x2){u1[rr].z, u1[rr].w} + (f32x2){vb.z, vb.w});
                int4v d;
                d.x = (int)cvt_pk_bf16(a0.x, a0.y);
                d.y = (int)cvt_pk_bf16(a1.x, a1.y);
                d.z = (int)cvt_pk_bf16(a2.x, a2.y);
                d.w = (int)cvt_pk_bf16(a3.x, a3.y);
                *(int4v*)(wbuf + rr * 512 + (c16 ^ (rr << 4))) = d;
            }
            flag_release_add(&prod_cnt[q], lane);
        }
    } else {
        // ================= CONSUMER (waves 4-7, one per SIMD) =================
        int wc = wv - 4;                  // col quarter: cols wc*64..+64
        int lr = lane & 15, lg = lane >> 4;

        // build Bf[8][4] straight from global w2 (same cvt_pk rounding as before)
        short8 Bf[8][4];
        #pragma unroll
        for (int ks = 0; ks < 8; ++ks)
            #pragma unroll
            for (int cg = 0; cg < 4; ++cg) {
                int n  = wc * 64 + cg * 16 + lr;
                int k0 = ks * 32 + lg * 8;
                const float* wp = w2 + k0 * 256 + n;
                union { short8 s; uint32_t w[4]; } A;
                A.w[0] = cvt_pk_bf16(wp[0],        wp[256]);
                A.w[1] = cvt_pk_bf16(wp[2 * 256],  wp[3 * 256]);
                A.w[2] = cvt_pk_bf16(wp[4 * 256],  wp[5 * 256]);
                A.w[3] = cvt_pk_bf16(wp[6 * 256],  wp[7 * 256]);
                Bf[ks][cg] = A.s;
            }

        f32x2 bias2[4];
        #pragma unroll
        for (int cg = 0; cg < 4; ++cg) {
            float bv = b2[wc * 64 + cg * 16 + lr];
            bias2[cg] = (f32x2){bv, bv};
        }

        int XB = (lg * 16) ^ ((lr & 7) << 4);
        int rE0 = lr * 512 + XB;
        int rO0 = lr * 512 + (XB ^ 64);

        f32x2 csum2[4];
        #pragma unroll
        for (int cg = 0; cg < 4; ++cg) csum2[cg] = (f32x2){0.f, 0.f};

        __syncthreads();   // matches producer barrier (us handoff)

        #pragma unroll 1
        for (int q = 0; q < 16; ++q) {
            spin_eq(&prod_cnt[q], 4);
            const char* base = (const char*)h1s[q & (NB - 1)];
            const char* hE = base + rE0;
            const char* hO = base + rO0;

            f32x4 acc[4][4];
            #pragma unroll
            for (int mi = 0; mi < 4; ++mi)
                #pragma unroll
                for (int cg = 0; cg < 4; ++cg) acc[mi][cg] = (f32x4){0.f, 0.f, 0.f, 0.f};

            short8 Aa[4], Ab[4];
            C_READ(Aa, 0) C_READ(Ab, 1)
            __builtin_amdgcn_s_setprio(1);
            C_MFMA(Aa, 0) C_READ(Aa, 2)
            C_MFMA(Ab, 1) C_READ(Ab, 3)
            C_MFMA(Aa, 2) C_READ(Aa, 4)
            C_MFMA(Ab, 3) C_READ(Ab, 5)
            C_MFMA(Aa, 4) C_READ(Aa, 6)
            C_MFMA(Ab, 5) C_READ(Ab, 7)
            C_MFMA(Aa, 6)
            C_MFMA(Ab, 7)
            __builtin_amdgcn_s_setprio(0);

            #pragma unroll
            for (int cg = 0; cg < 4; ++cg) {
                #pragma unroll
                for (int mi = 0; mi < 4; ++mi) {
                    f32x2 lo = relu2((f32x2){acc[mi][cg].x, acc[mi][cg].y} + bias2[cg]);
                    f32x2 hi = relu2((f32x2){acc[mi][cg].z, acc[mi][cg].w} + bias2[cg]);
                    csum2[cg] = csum2[cg] + lo + hi;
                }
            }
            flag_release_add(&cons_cnt[q], lane);
        }

        // flush: reduce over lg groups; lanes 0-15 store this wave's 64-col partial
        #pragma unroll
        for (int cg = 0; cg < 4; ++cg) {
            float s = csum2[cg].x + csum2[cg].y;
            s += __shfl_xor(s, 16);
            s += __shfl_xor(s, 32);
            if (lane < 16) part[(blk * 4 + wc) * 64 + cg * 16 + lr] = s;
        }
    }
}

// K5: pooled[b][c] = sum over 4 i-quarters of part[((b+64g)*4 + wc)*64 + cl]; then f-head.
__global__ void k5_head(const float* __restrict__ part, const float* __restrict__ fw1,
                        const float* __restrict__ fb1, const float* __restrict__ fw2,
                        const float* __restrict__ fb2, float* __restrict__ out) {
    __shared__ float P[256];
    __shared__ float wsum[4];
    int b = blockIdx.x, t = threadIdx.x;
    int wc = t >> 6, cl = t & 63;
    float s0 = 0.f;
    #pragma unroll
    for (int g = 0; g < 4; ++g)
        s0 += part[((b + 64 * g) * 4 + wc) * 64 + cl];
    P[t] = s0;
    __syncthreads();
    float a0 = 0.f, a1 = 0.f, a2 = 0.f, a3 = 0.f;
    for (int k = 0; k < 64; ++k) {
        a0 += P[k]       * fw1[k * 256 + t];
        a1 += P[k + 64]  * fw1[(k + 64) * 256 + t];
        a2 += P[k + 128] * fw1[(k + 128) * 256 + t];
        a3 += P[k + 192] * fw1[(k + 192) * 256 + t];
    }
    float h = fmaxf(fb1[t] + a0 + a1 + a2 + a3, 0.f);
    float p = h * fw2[t];
    #pragma unroll
    for (int off = 32; off >= 1; off >>= 1) p += __shfl_xor(p, off);
    if ((t & 63) == 0) wsum[t >> 6] = p;
    __syncthreads();
    if (t == 0) out[b] = wsum[0] + wsum[1] + wsum[2] + wsum[3] + fb2[0];
}

extern "C" void kernel_launch(void* const* d_in, const int* in_sizes, int n_in,
                              void* d_out, int out_size, void* d_ws, size_t ws_size,
                              hipStream_t stream) {
    const float* image  = (const float*)d_in[0];
    const float* conv_w = (const float*)d_in[1];
    const float* conv_b = (const float*)d_in[2];
    const float* g_w1   = (const float*)d_in[3];
    const float* g_b1   = (const float*)d_in[4];
    const float* g_w2   = (const float*)d_in[5];
    const float* g_b2   = (const float*)d_in[6];
    const float* f_w1   = (const float*)d_in[7];
    const float* f_b1   = (const float*)d_in[8];
    const float* f_w2   = (const float*)d_in[9];
    const float* f_b2   = (const float*)d_in[10];
    float* out = (float*)d_out;

    float* part = (float*)d_ws;   // 256*4*64*4 = 256 KB

    k_main<<<256, 512, 0, stream>>>(image, conv_w, conv_b, g_w1, g_b1, g_w2,
                                    g_b2, part);
    k5_head<<<64, 256, 0, stream>>>(part, f_w1, f_b1, f_w2, f_b2, out);
}